// Round 11
// baseline (547.825 us; speedup 1.0000x reference)
//
#include <hip/hip_runtime.h>

#define N_NODES 100000
#define N_EDGES 1000000
#define NB_SCAN 391  /* ceil(N/256) */
#define EDGE_OUT_BASE 1200000  /* N_NODES*12 elements */

typedef __attribute__((ext_vector_type(8))) short short8;
typedef __attribute__((ext_vector_type(4))) unsigned short us4;
typedef __attribute__((ext_vector_type(4))) float f32x4;

__device__ __forceinline__ float bf2f(unsigned short u) {
    unsigned int x = ((unsigned int)u) << 16;
    return __builtin_bit_cast(float, x);
}
__device__ __forceinline__ float lo_bf(unsigned int u) {
    return __builtin_bit_cast(float, u << 16);
}
__device__ __forceinline__ float hi_bf(unsigned int u) {
    return __builtin_bit_cast(float, u & 0xffff0000u);
}
__device__ __forceinline__ unsigned short f2bf(float f) {
    unsigned int x = __builtin_bit_cast(unsigned int, f);
    return (unsigned short)((x + 0x7fffu + ((x >> 16) & 1u)) >> 16);
}

// ---------------- dtype detection ----------------
__global__ __launch_bounds__(256) void k_detect(const unsigned short* __restrict__ xr,
                                                int* __restrict__ flag) {
    __shared__ int s[256];
    int t = threadIdx.x;
    int cnt = 0;
    for (int i = t; i < 8192; i += 256) {
        int e = (xr[i] >> 7) & 0xFF;
        if (e >= 148) cnt++;
    }
    s[t] = cnt;
    __syncthreads();
    for (int off = 128; off > 0; off >>= 1) {
        if (t < off) s[t] += s[t + off];
        __syncthreads();
    }
    if (t == 0) *flag = (s[0] > 100) ? 1 : 0;
}

// ---------------- weight canonicalization (any dtype -> bf16) ----------------
struct WPack { const void* p[14]; };
#define W_TOTAL 87888
__global__ __launch_bounds__(256) void k_convw(WPack wp, const int* __restrict__ flag,
                                               unsigned short* __restrict__ dst) {
    const int starts[15] = {0, 8192, 8320, 24704, 24832, 41216, 41344, 49536,
                            49600, 50368, 50380, 87244, 87372, 87884, 87888};
    bool f32 = (*flag != 0);
    int i = blockIdx.x * 256 + threadIdx.x;
    if (i >= W_TOTAL) return;
    int s = 0;
#pragma unroll
    for (int k = 1; k < 14; k++) s += (i >= starts[k]) ? 1 : 0;
    int j = i - starts[s];
    dst[i] = f32 ? f2bf(((const float*)wp.p[s])[j]) : ((const unsigned short*)wp.p[s])[j];
}
#define OW_We 0
#define OW_be 8192
#define OW_Wc1 8320
#define OW_bc1 24704
#define OW_Wc2 24832
#define OW_bc2 41216
#define OW_Wn1 41344
#define OW_bn1 49536
#define OW_Wn2 49600
#define OW_bn2 50368
#define OW_We1 50380
#define OW_be1 87244
#define OW_We2 87372
#define OW_be2 87884

// ---------------- graph build ----------------
__global__ __launch_bounds__(256) void k_hist(const int* __restrict__ ecol, int* __restrict__ deg) {
    int e = blockIdx.x * 256 + threadIdx.x;
    if (e < N_EDGES) atomicAdd(&deg[ecol[e]], 1);
}

__global__ __launch_bounds__(256) void k_scanA(const int* __restrict__ deg, int* __restrict__ bsum) {
    __shared__ int s[256];
    int i = blockIdx.x * 256 + threadIdx.x;
    s[threadIdx.x] = (i < N_NODES) ? deg[i] : 0;
    __syncthreads();
    for (int off = 128; off > 0; off >>= 1) {
        if (threadIdx.x < off) s[threadIdx.x] += s[threadIdx.x + off];
        __syncthreads();
    }
    if (threadIdx.x == 0) bsum[blockIdx.x] = s[0];
}

__global__ __launch_bounds__(512) void k_scanB(int* __restrict__ bsum) {
    __shared__ int s[512];
    int t = threadIdx.x;
    int v = (t < NB_SCAN) ? bsum[t] : 0;
    s[t] = v;
    __syncthreads();
    for (int off = 1; off < 512; off <<= 1) {
        int x = (t >= off) ? s[t - off] : 0;
        __syncthreads();
        s[t] += x;
        __syncthreads();
    }
    if (t < NB_SCAN) bsum[t] = s[t] - v;  // exclusive
}

__global__ __launch_bounds__(256) void k_scanC(const int* __restrict__ deg, const int* __restrict__ bsum,
                                               int* __restrict__ row_off, int* __restrict__ cursor,
                                               float* __restrict__ dinv) {
    __shared__ int s[256];
    int i = blockIdx.x * 256 + threadIdx.x;
    int t = threadIdx.x;
    int v = (i < N_NODES) ? deg[i] : 0;
    s[t] = v;
    __syncthreads();
    for (int off = 1; off < 256; off <<= 1) {
        int x = (t >= off) ? s[t - off] : 0;
        __syncthreads();
        s[t] += x;
        __syncthreads();
    }
    int excl = s[t] - v + bsum[blockIdx.x];
    if (i < N_NODES) {
        row_off[i] = excl;
        cursor[i] = excl;
        dinv[i] = rsqrtf((float)(v + 1));  // +1 self-loop
    }
    if (i == N_NODES - 1) row_off[N_NODES] = excl + v;
}

// fills conv csr (src node per position) AND edge-head aux ({orig edge id, col node})
__global__ __launch_bounds__(256) void k_fill(const int* __restrict__ erow, const int* __restrict__ ecol,
                                              int* __restrict__ cursor, int* __restrict__ csr,
                                              int2* __restrict__ aux) {
    int e = blockIdx.x * 256 + threadIdx.x;
    if (e < N_EDGES) {
        int c = ecol[e];
        int pos = atomicAdd(&cursor[c], 1);
        csr[pos] = erow[e];
        aux[pos] = make_int2(e, c);
    }
}

// ---------------- rows GEMM: Out[M,o_real] = act(A[M,K] @ W[K,o_real] + bias) [* rowscale] ----------------
template <int K, int O, bool RELU, bool BIAS, bool SCALE>
__global__ __launch_bounds__(256) void gemm_rows(const void* __restrict__ A, int M,
                                                 const unsigned short* __restrict__ W, int o_real,
                                                 const unsigned short* __restrict__ bias,
                                                 void* __restrict__ Out, int out_pitch,
                                                 const float* __restrict__ rowscale,
                                                 const int* aflag, const int* oflag) {
    constexpr int KP = K + 8;
    constexpr int KS = K / 32;
    constexpr int OT = O / 16;
    __shared__ short wt[O * KP];
    __shared__ float bias_s[O];
    int tid = threadIdx.x;
    for (int idx = tid; idx < K * O; idx += 256) {
        int k = idx / O, o = idx % O;
        short w = 0;
        if (o < o_real) w = (short)W[(size_t)k * o_real + o];
        wt[o * KP + k] = w;
    }
    if (BIAS) {
        for (int o = tid; o < O; o += 256) bias_s[o] = (o < o_real) ? bf2f(bias[o]) : 0.f;
    }
    __syncthreads();

    bool af32 = aflag && (*aflag != 0);
    bool of32 = oflag && (*oflag != 0);

    int wid = tid >> 6, lane = tid & 63;
    int rbase = (blockIdx.x * 4 + wid) * 32;
    if (rbase >= M) return;
    int lq = lane >> 4, lr = lane & 15;

    short8 a[2][KS];
#pragma unroll
    for (int rg = 0; rg < 2; rg++) {
        int row = rbase + rg * 16 + lr;
        if (row >= M) row = M - 1;
        if (af32) {
            const float* ap = (const float*)A + (size_t)row * K + lq * 8;
#pragma unroll
            for (int ks = 0; ks < KS; ks++) {
                f32x4 u0 = *(const f32x4*)(ap + ks * 32);
                f32x4 u1 = *(const f32x4*)(ap + ks * 32 + 4);
                short8 v;
                v[0] = (short)f2bf(u0[0]); v[1] = (short)f2bf(u0[1]);
                v[2] = (short)f2bf(u0[2]); v[3] = (short)f2bf(u0[3]);
                v[4] = (short)f2bf(u1[0]); v[5] = (short)f2bf(u1[1]);
                v[6] = (short)f2bf(u1[2]); v[7] = (short)f2bf(u1[3]);
                a[rg][ks] = v;
            }
        } else {
            const unsigned short* ap = (const unsigned short*)A + (size_t)row * K + lq * 8;
#pragma unroll
            for (int ks = 0; ks < KS; ks++) a[rg][ks] = *(const short8*)(ap + ks * 32);
        }
    }

    f32x4 acc[2][OT];
#pragma unroll
    for (int rg = 0; rg < 2; rg++)
#pragma unroll
        for (int j = 0; j < OT; j++) {
            acc[rg][j][0] = 0.f; acc[rg][j][1] = 0.f; acc[rg][j][2] = 0.f; acc[rg][j][3] = 0.f;
        }

#pragma unroll
    for (int j = 0; j < OT; j++) {
        short8 b[KS];
#pragma unroll
        for (int ks = 0; ks < KS; ks++)
            b[ks] = *(const short8*)(&wt[(lr + 16 * j) * KP + ks * 32 + lq * 8]);
#pragma unroll
        for (int rg = 0; rg < 2; rg++)
#pragma unroll
            for (int ks = 0; ks < KS; ks++)
                acc[rg][j] = __builtin_amdgcn_mfma_f32_16x16x32_bf16(a[rg][ks], b[ks], acc[rg][j], 0, 0, 0);
    }

    // D layout: col = lane&15, row = (lane>>4)*4 + reg
#pragma unroll
    for (int rg = 0; rg < 2; rg++)
#pragma unroll
        for (int j = 0; j < OT; j++)
#pragma unroll
            for (int r = 0; r < 4; r++) {
                int row = rbase + rg * 16 + lq * 4 + r;
                int col = lr + 16 * j;
                if (row < M && col < o_real) {
                    float v = acc[rg][j][r];
                    if (BIAS) v += bias_s[col];
                    if (RELU) v = fmaxf(v, 0.f);
                    if (SCALE) v *= rowscale[row];
                    size_t oi = (size_t)row * out_pitch + col;
                    if (of32) ((float*)Out)[oi] = v;
                    else ((unsigned short*)Out)[oi] = f2bf(v);
                }
            }
}

// ---------------- fused node head: logits = relu(h2@Wn1+bn1)@Wn2+bn2 ----------------
__global__ __launch_bounds__(256) void node_head(const unsigned short* __restrict__ A, int M,
                                                 const unsigned short* __restrict__ wbuf,
                                                 void* __restrict__ Out, const int* oflag) {
    __shared__ short wt1[64 * 136];  // Wn1^T [o][k], K=128
    __shared__ short zb[128 * 72];   // z[row][k], K=64, pitch 72
    __shared__ short wt2[16 * 72];   // Wn2^T [o][k], K=64 (12 real)
    __shared__ float b1[64];
    __shared__ float b2[16];
    int tid = threadIdx.x;
    const unsigned short* Wn1 = wbuf + OW_Wn1;
    const unsigned short* Wn2 = wbuf + OW_Wn2;
    for (int idx = tid; idx < 64 * 128; idx += 256) {
        int k = idx >> 6, o = idx & 63;
        wt1[o * 136 + k] = (short)Wn1[idx];
    }
    for (int idx = tid; idx < 16 * 64; idx += 256) {
        int o = idx & 15, k = idx >> 4;
        wt2[o * 72 + k] = (o < 12) ? (short)Wn2[k * 12 + o] : 0;
    }
    if (tid < 64) b1[tid] = bf2f(wbuf[OW_bn1 + tid]);
    if (tid < 16) b2[tid] = (tid < 12) ? bf2f(wbuf[OW_bn2 + tid]) : 0.f;
    __syncthreads();

    bool of32 = oflag && (*oflag != 0);
    int wid = tid >> 6, lane = tid & 63;
    int lq = lane >> 4, lr = lane & 15;
    int rbase = blockIdx.x * 128 + wid * 32;

    // A-frags K=128
    short8 a[2][4];
#pragma unroll
    for (int rg = 0; rg < 2; rg++) {
        int row = rbase + rg * 16 + lr;
        if (row >= M) row = M - 1;
        const unsigned short* ap = A + (size_t)row * 128 + lq * 8;
#pragma unroll
        for (int ks = 0; ks < 4; ks++) a[rg][ks] = *(const short8*)(ap + ks * 32);
    }

    // phase 1: z = relu(A@Wn1 + bn1), O=64 (OT=4)
    {
        f32x4 acc[2][4];
#pragma unroll
        for (int rg = 0; rg < 2; rg++)
#pragma unroll
            for (int j = 0; j < 4; j++) {
                acc[rg][j][0] = 0.f; acc[rg][j][1] = 0.f; acc[rg][j][2] = 0.f; acc[rg][j][3] = 0.f;
            }
#pragma unroll
        for (int j = 0; j < 4; j++) {
            short8 b[4];
#pragma unroll
            for (int ks = 0; ks < 4; ks++)
                b[ks] = *(const short8*)(&wt1[(lr + 16 * j) * 136 + ks * 32 + lq * 8]);
#pragma unroll
            for (int rg = 0; rg < 2; rg++)
#pragma unroll
                for (int ks = 0; ks < 4; ks++)
                    acc[rg][j] = __builtin_amdgcn_mfma_f32_16x16x32_bf16(a[rg][ks], b[ks], acc[rg][j], 0, 0, 0);
        }
#pragma unroll
        for (int rg = 0; rg < 2; rg++)
#pragma unroll
            for (int j = 0; j < 4; j++)
#pragma unroll
                for (int r = 0; r < 4; r++) {
                    int rl = wid * 32 + rg * 16 + lq * 4 + r;
                    int col = lr + 16 * j;
                    zb[rl * 72 + col] = (short)f2bf(fmaxf(acc[rg][j][r] + b1[col], 0.f));
                }
    }
    __syncthreads();

    // phase 2: logits = z@Wn2 + bn2, K=64, O=16 (12 real)
    {
        short8 a2[2][2];
#pragma unroll
        for (int rg = 0; rg < 2; rg++) {
            int rl = wid * 32 + rg * 16 + lr;
#pragma unroll
            for (int ks = 0; ks < 2; ks++)
                a2[rg][ks] = *(const short8*)(&zb[rl * 72 + ks * 32 + lq * 8]);
        }
        short8 b[2];
#pragma unroll
        for (int ks = 0; ks < 2; ks++)
            b[ks] = *(const short8*)(&wt2[lr * 72 + ks * 32 + lq * 8]);
        f32x4 acc[2];
#pragma unroll
        for (int rg = 0; rg < 2; rg++) {
            acc[rg][0] = 0.f; acc[rg][1] = 0.f; acc[rg][2] = 0.f; acc[rg][3] = 0.f;
#pragma unroll
            for (int ks = 0; ks < 2; ks++)
                acc[rg] = __builtin_amdgcn_mfma_f32_16x16x32_bf16(a2[rg][ks], b[ks], acc[rg], 0, 0, 0);
        }
#pragma unroll
        for (int rg = 0; rg < 2; rg++)
#pragma unroll
            for (int r = 0; r < 4; r++) {
                int row = rbase + rg * 16 + lq * 4 + r;
                int col = lr;
                if (row < M && col < 12) {
                    float v = acc[rg][r] + b2[col];
                    size_t oi = (size_t)row * 12 + col;
                    if (of32) ((float*)Out)[oi] = v;
                    else ((unsigned short*)Out)[oi] = f2bf(v);
                }
            }
    }
}

// ---------------- dual GEMM for edge-head P/Q — PERMUTED channel layout ----------------
__global__ __launch_bounds__(256) void gemm_pq(const unsigned short* __restrict__ A, int M,
                                               const unsigned short* __restrict__ W1,
                                               const unsigned short* __restrict__ W2,
                                               unsigned short* __restrict__ Pout,
                                               unsigned short* __restrict__ Qout) {
    __shared__ short wt[128 * 136];
    int tid = threadIdx.x;
    int wid = tid >> 6, lane = tid & 63;
    int rbase = (blockIdx.x * 4 + wid) * 32;
    int lq = lane >> 4, lr = lane & 15;

    // A fragments (loaded once, before ANY store)
    short8 a[2][4];
#pragma unroll
    for (int rg = 0; rg < 2; rg++) {
        int row = rbase + rg * 16 + lr;
        if (row >= M) row = M - 1;
        const unsigned short* ap = A + (size_t)row * 128 + lq * 8;
#pragma unroll
        for (int ks = 0; ks < 4; ks++) a[rg][ks] = *(const short8*)(ap + ks * 32);
    }

    // col = lr + 16j -> permuted position = (lr>>2)*32 + j*4 + (lr&3)
    int pc0 = (lr >> 2) * 32 + (lr & 3);

    // ---- phase P ----
    for (int idx = tid; idx < 128 * 128; idx += 256) {
        int k = idx >> 7, o = idx & 127;
        wt[o * 136 + k] = (short)W1[idx];
    }
    __syncthreads();
    {
        f32x4 acc[2][8];
#pragma unroll
        for (int rg = 0; rg < 2; rg++)
#pragma unroll
            for (int j = 0; j < 8; j++) {
                acc[rg][j][0] = 0.f; acc[rg][j][1] = 0.f; acc[rg][j][2] = 0.f; acc[rg][j][3] = 0.f;
            }
#pragma unroll
        for (int j = 0; j < 8; j++) {
            short8 b[4];
#pragma unroll
            for (int ks = 0; ks < 4; ks++)
                b[ks] = *(const short8*)(&wt[(lr + 16 * j) * 136 + ks * 32 + lq * 8]);
#pragma unroll
            for (int rg = 0; rg < 2; rg++)
#pragma unroll
                for (int ks = 0; ks < 4; ks++)
                    acc[rg][j] = __builtin_amdgcn_mfma_f32_16x16x32_bf16(a[rg][ks], b[ks], acc[rg][j], 0, 0, 0);
        }
#pragma unroll
        for (int rg = 0; rg < 2; rg++)
#pragma unroll
            for (int j = 0; j < 8; j++)
#pragma unroll
                for (int r = 0; r < 4; r++) {
                    int row = rbase + rg * 16 + lq * 4 + r;
                    if (row < M) Pout[(size_t)row * 128 + pc0 + j * 4] = f2bf(acc[rg][j][r]);
                }
    }
    __syncthreads();

    // ---- phase Q ----
    for (int idx = tid; idx < 128 * 128; idx += 256) {
        int k = idx >> 7, o = idx & 127;
        wt[o * 136 + k] = (short)W2[idx];
    }
    __syncthreads();
    {
        f32x4 acc[2][8];
#pragma unroll
        for (int rg = 0; rg < 2; rg++)
#pragma unroll
            for (int j = 0; j < 8; j++) {
                acc[rg][j][0] = 0.f; acc[rg][j][1] = 0.f; acc[rg][j][2] = 0.f; acc[rg][j][3] = 0.f;
            }
#pragma unroll
        for (int j = 0; j < 8; j++) {
            short8 b[4];
#pragma unroll
            for (int ks = 0; ks < 4; ks++)
                b[ks] = *(const short8*)(&wt[(lr + 16 * j) * 136 + ks * 32 + lq * 8]);
#pragma unroll
            for (int rg = 0; rg < 2; rg++)
#pragma unroll
                for (int ks = 0; ks < 4; ks++)
                    acc[rg][j] = __builtin_amdgcn_mfma_f32_16x16x32_bf16(a[rg][ks], b[ks], acc[rg][j], 0, 0, 0);
        }
#pragma unroll
        for (int rg = 0; rg < 2; rg++)
#pragma unroll
            for (int j = 0; j < 8; j++)
#pragma unroll
                for (int r = 0; r < 4; r++) {
                    int row = rbase + rg * 16 + lq * 4 + r;
                    if (row < M) Qout[(size_t)row * 128 + pc0 + j * 4] = f2bf(acc[rg][j][r]);
                }
    }
}

// ---------------- GCN conv: 4 nodes/wave, contiguous-CSR 8-deep window pipeline ----------------
// 4 consecutive nodes own a CONTIGUOUS csr position range [b0,b4). Ping-pong 8-wide
// chunks keep ~8 row-gathers in flight continuously (degree boundaries don't stall).
// Node-select per position is wave-uniform (scalar branch). Arrays statically indexed
// via full unroll (rule #20).
#define CONV_LOADC(U, base)                                                             \
    _Pragma("unroll") for (int k = 0; k < 8; k++) {                                     \
        int p = (base) + k;                                                             \
        int pc = (p < cend) ? p : (cend - 1);                                           \
        int s = csr_src[pc];                                                            \
        U[k] = *(const unsigned int*)(xw_s + (size_t)s * 128 + lane * 2);               \
    }
#define CONV_CONSUME(U, base)                                                           \
    _Pragma("unroll") for (int k = 0; k < 8; k++) {                                     \
        int p = (base) + k;                                                             \
        if (p < cend) {                                                                 \
            float lo = lo_bf(U[k]), hi = hi_bf(U[k]);                                   \
            if (p >= b3)      { A3l += lo; A3h += hi; }                                 \
            else if (p >= b2) { A2l += lo; A2h += hi; }                                 \
            else if (p >= b1) { A1l += lo; A1h += hi; }                                 \
            else              { A0l += lo; A0h += hi; }                                 \
        }                                                                               \
    }
__global__ __launch_bounds__(256) void conv_kernel(const unsigned short* __restrict__ xw_s,
                                                   const int* __restrict__ csr_src,
                                                   const int* __restrict__ row_off,
                                                   const float* __restrict__ dinv,
                                                   const unsigned short* __restrict__ bias,
                                                   unsigned short* __restrict__ out) {
    int wid = threadIdx.x >> 6, lane = threadIdx.x & 63;
    int t0 = (blockIdx.x * 4 + wid) * 4;  // grid = N/16, N%16==0
    int b0 = row_off[t0], b1 = row_off[t0 + 1], b2 = row_off[t0 + 2];
    int b3 = row_off[t0 + 3], cend = row_off[t0 + 4];

    // self terms (xw_s prescaled by dinv[src]; self weight dinv[t]^2 handled by final *dinv[t])
    unsigned int v0 = *(const unsigned int*)(xw_s + (size_t)(t0 + 0) * 128 + lane * 2);
    unsigned int v1 = *(const unsigned int*)(xw_s + (size_t)(t0 + 1) * 128 + lane * 2);
    unsigned int v2 = *(const unsigned int*)(xw_s + (size_t)(t0 + 2) * 128 + lane * 2);
    unsigned int v3 = *(const unsigned int*)(xw_s + (size_t)(t0 + 3) * 128 + lane * 2);
    float A0l = lo_bf(v0), A0h = hi_bf(v0);
    float A1l = lo_bf(v1), A1h = hi_bf(v1);
    float A2l = lo_bf(v2), A2h = hi_bf(v2);
    float A3l = lo_bf(v3), A3h = hi_bf(v3);

    if (b0 < cend) {
        unsigned int UA[8], UB[8];
        int i = b0;
        CONV_LOADC(UA, i);
        while (true) {
            bool hasB = (i + 8) < cend;
            if (hasB) { CONV_LOADC(UB, i + 8); }
            CONV_CONSUME(UA, i);
            i += 8;
            if (!hasB) break;
            bool hasA = (i + 8) < cend;
            if (hasA) { CONV_LOADC(UA, i + 8); }
            CONV_CONSUME(UB, i);
            i += 8;
            if (!hasA) break;
        }
    }

    unsigned int bv = *(const unsigned int*)(bias + lane * 2);
    float bl = lo_bf(bv), bh = hi_bf(bv);
    float d0 = dinv[t0], d1 = dinv[t0 + 1], d2 = dinv[t0 + 2], d3 = dinv[t0 + 3];
    A0l = fmaxf(fmaf(A0l, d0, bl), 0.f); A0h = fmaxf(fmaf(A0h, d0, bh), 0.f);
    A1l = fmaxf(fmaf(A1l, d1, bl), 0.f); A1h = fmaxf(fmaf(A1h, d1, bh), 0.f);
    A2l = fmaxf(fmaf(A2l, d2, bl), 0.f); A2h = fmaxf(fmaf(A2h, d2, bh), 0.f);
    A3l = fmaxf(fmaf(A3l, d3, bl), 0.f); A3h = fmaxf(fmaf(A3h, d3, bh), 0.f);
    *(unsigned int*)(out + (size_t)(t0 + 0) * 128 + lane * 2) =
        (unsigned int)f2bf(A0l) | ((unsigned int)f2bf(A0h) << 16);
    *(unsigned int*)(out + (size_t)(t0 + 1) * 128 + lane * 2) =
        (unsigned int)f2bf(A1l) | ((unsigned int)f2bf(A1h) << 16);
    *(unsigned int*)(out + (size_t)(t0 + 2) * 128 + lane * 2) =
        (unsigned int)f2bf(A2l) | ((unsigned int)f2bf(A2h) << 16);
    *(unsigned int*)(out + (size_t)(t0 + 3) * 128 + lane * 2) =
        (unsigned int)f2bf(A3l) | ((unsigned int)f2bf(A3h) << 16);
}

// ---------------- edge head epilogue chunk helper ----------------
__device__ __forceinline__ void epi_chunk(f32x4& ov, const f32x4& acc_lo, const f32x4& acc_hi,
                                          short8 pv, short8 qv,
                                          const float* __restrict__ b1s,
                                          const float* __restrict__ w2s, int pb) {
#pragma unroll
    for (int jj = 0; jj < 2; jj++) {
        const f32x4& ac = jj ? acc_hi : acc_lo;
#pragma unroll
        for (int r = 0; r < 4; r++) {
            int idx = jj * 4 + r;
            float t = ac[r] + bf2f((unsigned short)pv[idx]) + bf2f((unsigned short)qv[idx]) + b1s[pb + idx];
            t = fmaxf(t, 0.f);
            f32x4 w2v = *(const f32x4*)(&w2s[(pb + idx) * 4]);
            ov[0] = fmaf(t, w2v[0], ov[0]);
            ov[1] = fmaf(t, w2v[1], ov[1]);
            ov[2] = fmaf(t, w2v[2], ov[2]);
            ov[3] = fmaf(t, w2v[3], ov[3]);
        }
    }
}

// ---------------- fused edge head: CSR-ordered (round-9 version — measured floor 113us) ----------------
__global__ __launch_bounds__(256) void edge_head(const void* __restrict__ ea,
                                                 const int* __restrict__ csr_src,
                                                 const int2* __restrict__ aux,
                                                 const unsigned short* __restrict__ P,
                                                 const unsigned short* __restrict__ Q,
                                                 const unsigned short* __restrict__ wbuf,
                                                 void* __restrict__ out, const int* dtflag) {
    __shared__ short wct[128 * 40];  // Wc3^T [ch][k], pitch 40
    __shared__ float w2s[128 * 4];   // permuted
    __shared__ float b1s[128];       // permuted
    int tid = threadIdx.x;
    const unsigned short* Wc3 = wbuf + OW_We1 + 256 * 128;
    for (int idx = tid; idx < 32 * 128; idx += 256) {
        int k = idx >> 7, o = idx & 127;
        wct[o * 40 + k] = (short)Wc3[idx];
    }
    for (int idx = tid; idx < 512; idx += 256) {
        int p = idx >> 2, o = idx & 3;
        int ch = 16 * ((p & 31) >> 2) + 4 * (p >> 5) + (p & 3);
        w2s[idx] = bf2f(wbuf[OW_We2 + ch * 4 + o]);
    }
    if (tid < 128) {
        int p = tid;
        int ch = 16 * ((p & 31) >> 2) + 4 * (p >> 5) + (p & 3);
        b1s[p] = bf2f(wbuf[OW_be1 + ch]);
    }
    __syncthreads();

    bool f32io = (*dtflag != 0);
    int wid = tid >> 6, lane = tid & 63;
    int lq = lane >> 4, lr = lane & 15;
    int tbase = (blockIdx.x * 4 + wid) * 2;
    int p0a = tbase * 16, p0b = p0a + 16;

    int posa = p0a + lr, posb = p0b + lr;
    bool va = posa < N_EDGES, vb = posb < N_EDGES;
    int pca = va ? posa : (N_EDGES - 1);
    int pcb = vb ? posb : (N_EDGES - 1);

    int rna = csr_src[pca], rnb = csr_src[pcb];
    int2 axa = aux[pca], axb = aux[pcb];
    int gea = axa.x, cna = axa.y;
    int geb = axb.x, cnb = axb.y;

    auto load_efrag = [&](int ge) -> short8 {
        short8 v;
        if (f32io) {
            const float* eap = (const float*)ea + (size_t)ge * 32 + lq * 8;
            f32x4 u0 = __builtin_nontemporal_load((const f32x4*)eap);
            f32x4 u1 = __builtin_nontemporal_load((const f32x4*)(eap + 4));
            v[0] = (short)f2bf(u0[0]); v[1] = (short)f2bf(u0[1]);
            v[2] = (short)f2bf(u0[2]); v[3] = (short)f2bf(u0[3]);
            v[4] = (short)f2bf(u1[0]); v[5] = (short)f2bf(u1[1]);
            v[6] = (short)f2bf(u1[2]); v[7] = (short)f2bf(u1[3]);
        } else {
            v = __builtin_nontemporal_load((const short8*)((const unsigned short*)ea + (size_t)ge * 32 + lq * 8));
        }
        return v;
    };
    short8 efA = load_efrag(gea);
    short8 efB = load_efrag(geb);

    const unsigned short* PpA = P + (size_t)rna * 128 + lq * 32;
    const unsigned short* QpA = Q + (size_t)cna * 128 + lq * 32;
    const unsigned short* PpB = P + (size_t)rnb * 128 + lq * 32;
    const unsigned short* QpB = Q + (size_t)cnb * 128 + lq * 32;

    f32x4 zero; zero[0] = 0.f; zero[1] = 0.f; zero[2] = 0.f; zero[3] = 0.f;
    f32x4 ovA = zero, ovB = zero;

    // ---- half 0: channels 0..63 (j=0..3) ----
    {
        short8 pA0 = *(const short8*)(PpA + 0);
        short8 pA1 = *(const short8*)(PpA + 8);
        short8 qA0 = *(const short8*)(QpA + 0);
        short8 qA1 = *(const short8*)(QpA + 8);
        short8 pB0 = *(const short8*)(PpB + 0);
        short8 pB1 = *(const short8*)(PpB + 8);
        short8 qB0 = *(const short8*)(QpB + 0);
        short8 qB1 = *(const short8*)(QpB + 8);
        short8 wf0 = *(const short8*)(&wct[(0 * 16 + lr) * 40 + lq * 8]);
        short8 wf1 = *(const short8*)(&wct[(1 * 16 + lr) * 40 + lq * 8]);
        short8 wf2 = *(const short8*)(&wct[(2 * 16 + lr) * 40 + lq * 8]);
        short8 wf3 = *(const short8*)(&wct[(3 * 16 + lr) * 40 + lq * 8]);
        f32x4 aA0 = __builtin_amdgcn_mfma_f32_16x16x32_bf16(wf0, efA, zero, 0, 0, 0);
        f32x4 aA1 = __builtin_amdgcn_mfma_f32_16x16x32_bf16(wf1, efA, zero, 0, 0, 0);
        f32x4 aA2 = __builtin_amdgcn_mfma_f32_16x16x32_bf16(wf2, efA, zero, 0, 0, 0);
        f32x4 aA3 = __builtin_amdgcn_mfma_f32_16x16x32_bf16(wf3, efA, zero, 0, 0, 0);
        f32x4 aB0 = __builtin_amdgcn_mfma_f32_16x16x32_bf16(wf0, efB, zero, 0, 0, 0);
        f32x4 aB1 = __builtin_amdgcn_mfma_f32_16x16x32_bf16(wf1, efB, zero, 0, 0, 0);
        f32x4 aB2 = __builtin_amdgcn_mfma_f32_16x16x32_bf16(wf2, efB, zero, 0, 0, 0);
        f32x4 aB3 = __builtin_amdgcn_mfma_f32_16x16x32_bf16(wf3, efB, zero, 0, 0, 0);
        epi_chunk(ovA, aA0, aA1, pA0, qA0, b1s, w2s, lq * 32 + 0);
        epi_chunk(ovA, aA2, aA3, pA1, qA1, b1s, w2s, lq * 32 + 8);
        epi_chunk(ovB, aB0, aB1, pB0, qB0, b1s, w2s, lq * 32 + 0);
        epi_chunk(ovB, aB2, aB3, pB1, qB1, b1s, w2s, lq * 32 + 8);
    }
    // ---- half 1: channels 64..127 (j=4..7) ----
    {
        short8 pA0 = *(const short8*)(PpA + 16);
        short8 pA1 = *(const short8*)(PpA + 24);
        short8 qA0 = *(const short8*)(QpA + 16);
        short8 qA1 = *(const short8*)(QpA + 24);
        short8 pB0 = *(const short8*)(PpB + 16);
        short8 pB1 = *(const short8*)(PpB + 24);
        short8 qB0 = *(const short8*)(QpB + 16);
        short8 qB1 = *(const short8*)(QpB + 24);
        short8 wf0 = *(const short8*)(&wct[(4 * 16 + lr) * 40 + lq * 8]);
        short8 wf1 = *(const short8*)(&wct[(5 * 16 + lr) * 40 + lq * 8]);
        short8 wf2 = *(const short8*)(&wct[(6 * 16 + lr) * 40 + lq * 8]);
        short8 wf3 = *(const short8*)(&wct[(7 * 16 + lr) * 40 + lq * 8]);
        f32x4 aA0 = __builtin_amdgcn_mfma_f32_16x16x32_bf16(wf0, efA, zero, 0, 0, 0);
        f32x4 aA1 = __builtin_amdgcn_mfma_f32_16x16x32_bf16(wf1, efA, zero, 0, 0, 0);
        f32x4 aA2 = __builtin_amdgcn_mfma_f32_16x16x32_bf16(wf2, efA, zero, 0, 0, 0);
        f32x4 aA3 = __builtin_amdgcn_mfma_f32_16x16x32_bf16(wf3, efA, zero, 0, 0, 0);
        f32x4 aB0 = __builtin_amdgcn_mfma_f32_16x16x32_bf16(wf0, efB, zero, 0, 0, 0);
        f32x4 aB1 = __builtin_amdgcn_mfma_f32_16x16x32_bf16(wf1, efB, zero, 0, 0, 0);
        f32x4 aB2 = __builtin_amdgcn_mfma_f32_16x16x32_bf16(wf2, efB, zero, 0, 0, 0);
        f32x4 aB3 = __builtin_amdgcn_mfma_f32_16x16x32_bf16(wf3, efB, zero, 0, 0, 0);
        epi_chunk(ovA, aA0, aA1, pA0, qA0, b1s, w2s, lq * 32 + 16);
        epi_chunk(ovA, aA2, aA3, pA1, qA1, b1s, w2s, lq * 32 + 24);
        epi_chunk(ovB, aB0, aB1, pB0, qB0, b1s, w2s, lq * 32 + 16);
        epi_chunk(ovB, aB2, aB3, pB1, qB1, b1s, w2s, lq * 32 + 24);
    }

    // reduce across lq (lane bits 4,5)
#pragma unroll
    for (int c = 0; c < 4; c++) {
        ovA[c] += __shfl_xor(ovA[c], 16);
        ovA[c] += __shfl_xor(ovA[c], 32);
        ovB[c] += __shfl_xor(ovB[c], 16);
        ovB[c] += __shfl_xor(ovB[c], 32);
    }
    if (lq == 0) {
        float be2_0 = bf2f(wbuf[OW_be2 + 0]), be2_1 = bf2f(wbuf[OW_be2 + 1]);
        float be2_2 = bf2f(wbuf[OW_be2 + 2]), be2_3 = bf2f(wbuf[OW_be2 + 3]);
        if (va) {
            size_t oi = (size_t)EDGE_OUT_BASE + (size_t)gea * 4;
            if (f32io) {
                f32x4 res; res[0] = ovA[0] + be2_0; res[1] = ovA[1] + be2_1;
                res[2] = ovA[2] + be2_2; res[3] = ovA[3] + be2_3;
                __builtin_nontemporal_store(res, (f32x4*)((float*)out + oi));
            } else {
                us4 res; res[0] = f2bf(ovA[0] + be2_0); res[1] = f2bf(ovA[1] + be2_1);
                res[2] = f2bf(ovA[2] + be2_2); res[3] = f2bf(ovA[3] + be2_3);
                __builtin_nontemporal_store(res, (us4*)((unsigned short*)out + oi));
            }
        }
        if (vb) {
            size_t oi = (size_t)EDGE_OUT_BASE + (size_t)geb * 4;
            if (f32io) {
                f32x4 res; res[0] = ovB[0] + be2_0; res[1] = ovB[1] + be2_1;
                res[2] = ovB[2] + be2_2; res[3] = ovB[3] + be2_3;
                __builtin_nontemporal_store(res, (f32x4*)((float*)out + oi));
            } else {
                us4 res; res[0] = f2bf(ovB[0] + be2_0); res[1] = f2bf(ovB[1] + be2_1);
                res[2] = f2bf(ovB[2] + be2_2); res[3] = f2bf(ovB[3] + be2_3);
                __builtin_nontemporal_store(res, (us4*)((unsigned short*)out + oi));
            }
        }
    }
}

// ---------------- launcher ----------------
extern "C" void kernel_launch(void* const* d_in, const int* in_sizes, int n_in,
                              void* d_out, int out_size, void* d_ws, size_t ws_size,
                              hipStream_t stream) {
    const void* x = d_in[0];
    const int* ei = (const int*)d_in[1];
    const void* ea = d_in[2];
    const int* erow = ei;
    const int* ecol = ei + N_EDGES;

    char* ws = (char*)d_ws;
    size_t off = 0;
    auto alloc = [&](size_t bytes) -> void* {
        void* p = ws + off;
        off += (bytes + 255) & ~(size_t)255;
        return p;
    };
    unsigned short* Abuf = (unsigned short*)alloc((size_t)N_NODES * 128 * 2);
    unsigned short* Bbuf = (unsigned short*)alloc((size_t)N_NODES * 128 * 2);
    int* deg = (int*)alloc((size_t)N_NODES * 4);
    int* row_off = (int*)alloc((size_t)(N_NODES + 1) * 4);
    int* cursor = (int*)alloc((size_t)N_NODES * 4);
    int* csr = (int*)alloc((size_t)N_EDGES * 4);
    int2* aux = (int2*)alloc((size_t)N_EDGES * 8);
    int* bsum = (int*)alloc(512 * 4);
    float* dinv = (float*)alloc((size_t)N_NODES * 4);
    unsigned short* wbuf = (unsigned short*)alloc((size_t)W_TOTAL * 2);
    int* dtflag = (int*)alloc(256);

    // 1. dtype detection (device-side)
    k_detect<<<1, 256, 0, stream>>>((const unsigned short*)x, dtflag);

    // 2. canonicalize weights to bf16
    WPack wp;
    for (int i = 0; i < 14; i++) wp.p[i] = d_in[3 + i];
    k_convw<<<(W_TOTAL + 255) / 256, 256, 0, stream>>>(wp, dtflag, wbuf);

    // 3. graph build
    (void)hipMemsetAsync(deg, 0, (size_t)N_NODES * 4, stream);
    k_hist<<<(N_EDGES + 255) / 256, 256, 0, stream>>>(ecol, deg);
    k_scanA<<<NB_SCAN, 256, 0, stream>>>(deg, bsum);
    k_scanB<<<1, 512, 0, stream>>>(bsum);
    k_scanC<<<NB_SCAN, 256, 0, stream>>>(deg, bsum, row_off, cursor, dinv);
    k_fill<<<(N_EDGES + 255) / 256, 256, 0, stream>>>(erow, ecol, cursor, csr, aux);

    int gB = (N_NODES + 127) / 128;
    // embed: h0 = relu(x@We+be) -> Abuf
    gemm_rows<64, 128, true, true, false><<<gB, 256, 0, stream>>>(x, N_NODES, wbuf + OW_We, 128, wbuf + OW_be, Abuf, 128, nullptr, dtflag, nullptr);
    // xw1_scaled = (h0@Wc1) * dinv[row] -> Bbuf
    gemm_rows<128, 128, false, false, true><<<gB, 256, 0, stream>>>(Abuf, N_NODES, wbuf + OW_Wc1, 128, nullptr, Bbuf, 128, dinv, nullptr, nullptr);
    conv_kernel<<<N_NODES / 16, 256, 0, stream>>>(Bbuf, csr, row_off, dinv, wbuf + OW_bc1, Abuf);
    // xw2_scaled = (h1@Wc2) * dinv[row] -> Bbuf
    gemm_rows<128, 128, false, false, true><<<gB, 256, 0, stream>>>(Abuf, N_NODES, wbuf + OW_Wc2, 128, nullptr, Bbuf, 128, dinv, nullptr, nullptr);
    conv_kernel<<<N_NODES / 16, 256, 0, stream>>>(Bbuf, csr, row_off, dinv, wbuf + OW_bc2, Abuf);
    // fused node head: logits -> d_out
    node_head<<<gB, 256, 0, stream>>>(Abuf, N_NODES, wbuf, d_out, dtflag);
    // edge head precompute (dual, permuted): P -> Bbuf, Q -> Abuf (in-place safe)
    gemm_pq<<<gB, 256, 0, stream>>>(Abuf, N_NODES, wbuf + OW_We1, wbuf + OW_We1 + 128 * 128, Bbuf, Abuf);
    // fused edge head: CSR-ordered (round-9 version), 128 positions per block
    edge_head<<<(N_EDGES + 127) / 128, 256, 0, stream>>>(ea, csr, aux, Bbuf, Abuf, wbuf, d_out, dtflag);
}

// Round 12
// 528.506 us; speedup vs baseline: 1.0366x; 1.0366x over previous
//
#include <hip/hip_runtime.h>

#define N_NODES 100000
#define N_EDGES 1000000
#define NB_SCAN 391  /* ceil(N/256) */
#define EDGE_OUT_BASE 1200000  /* N_NODES*12 elements */

typedef __attribute__((ext_vector_type(8))) short short8;
typedef __attribute__((ext_vector_type(4))) unsigned short us4;
typedef __attribute__((ext_vector_type(4))) float f32x4;

__device__ __forceinline__ float bf2f(unsigned short u) {
    unsigned int x = ((unsigned int)u) << 16;
    return __builtin_bit_cast(float, x);
}
__device__ __forceinline__ float lo_bf(unsigned int u) {
    return __builtin_bit_cast(float, u << 16);
}
__device__ __forceinline__ float hi_bf(unsigned int u) {
    return __builtin_bit_cast(float, u & 0xffff0000u);
}
__device__ __forceinline__ unsigned short f2bf(float f) {
    unsigned int x = __builtin_bit_cast(unsigned int, f);
    return (unsigned short)((x + 0x7fffu + ((x >> 16) & 1u)) >> 16);
}

// ---------------- dtype detection ----------------
__global__ __launch_bounds__(256) void k_detect(const unsigned short* __restrict__ xr,
                                                int* __restrict__ flag) {
    __shared__ int s[256];
    int t = threadIdx.x;
    int cnt = 0;
    for (int i = t; i < 8192; i += 256) {
        int e = (xr[i] >> 7) & 0xFF;
        if (e >= 148) cnt++;
    }
    s[t] = cnt;
    __syncthreads();
    for (int off = 128; off > 0; off >>= 1) {
        if (t < off) s[t] += s[t + off];
        __syncthreads();
    }
    if (t == 0) *flag = (s[0] > 100) ? 1 : 0;
}

// ---------------- weight canonicalization (any dtype -> bf16) ----------------
struct WPack { const void* p[14]; };
#define W_TOTAL 87888
__global__ __launch_bounds__(256) void k_convw(WPack wp, const int* __restrict__ flag,
                                               unsigned short* __restrict__ dst) {
    const int starts[15] = {0, 8192, 8320, 24704, 24832, 41216, 41344, 49536,
                            49600, 50368, 50380, 87244, 87372, 87884, 87888};
    bool f32 = (*flag != 0);
    int i = blockIdx.x * 256 + threadIdx.x;
    if (i >= W_TOTAL) return;
    int s = 0;
#pragma unroll
    for (int k = 1; k < 14; k++) s += (i >= starts[k]) ? 1 : 0;
    int j = i - starts[s];
    dst[i] = f32 ? f2bf(((const float*)wp.p[s])[j]) : ((const unsigned short*)wp.p[s])[j];
}
#define OW_We 0
#define OW_be 8192
#define OW_Wc1 8320
#define OW_bc1 24704
#define OW_Wc2 24832
#define OW_bc2 41216
#define OW_Wn1 41344
#define OW_bn1 49536
#define OW_Wn2 49600
#define OW_bn2 50368
#define OW_We1 50380
#define OW_be1 87244
#define OW_We2 87372
#define OW_be2 87884

// ---------------- graph build ----------------
__global__ __launch_bounds__(256) void k_hist(const int* __restrict__ ecol, int* __restrict__ deg) {
    int e = blockIdx.x * 256 + threadIdx.x;
    if (e < N_EDGES) atomicAdd(&deg[ecol[e]], 1);
}

__global__ __launch_bounds__(256) void k_scanA(const int* __restrict__ deg, int* __restrict__ bsum) {
    __shared__ int s[256];
    int i = blockIdx.x * 256 + threadIdx.x;
    s[threadIdx.x] = (i < N_NODES) ? deg[i] : 0;
    __syncthreads();
    for (int off = 128; off > 0; off >>= 1) {
        if (threadIdx.x < off) s[threadIdx.x] += s[threadIdx.x + off];
        __syncthreads();
    }
    if (threadIdx.x == 0) bsum[blockIdx.x] = s[0];
}

__global__ __launch_bounds__(512) void k_scanB(int* __restrict__ bsum) {
    __shared__ int s[512];
    int t = threadIdx.x;
    int v = (t < NB_SCAN) ? bsum[t] : 0;
    s[t] = v;
    __syncthreads();
    for (int off = 1; off < 512; off <<= 1) {
        int x = (t >= off) ? s[t - off] : 0;
        __syncthreads();
        s[t] += x;
        __syncthreads();
    }
    if (t < NB_SCAN) bsum[t] = s[t] - v;  // exclusive
}

__global__ __launch_bounds__(256) void k_scanC(const int* __restrict__ deg, const int* __restrict__ bsum,
                                               int* __restrict__ row_off, int* __restrict__ cursor,
                                               float* __restrict__ dinv) {
    __shared__ int s[256];
    int i = blockIdx.x * 256 + threadIdx.x;
    int t = threadIdx.x;
    int v = (i < N_NODES) ? deg[i] : 0;
    s[t] = v;
    __syncthreads();
    for (int off = 1; off < 256; off <<= 1) {
        int x = (t >= off) ? s[t - off] : 0;
        __syncthreads();
        s[t] += x;
        __syncthreads();
    }
    int excl = s[t] - v + bsum[blockIdx.x];
    if (i < N_NODES) {
        row_off[i] = excl;
        cursor[i] = excl;
        dinv[i] = rsqrtf((float)(v + 1));  // +1 self-loop
    }
    if (i == N_NODES - 1) row_off[N_NODES] = excl + v;
}

// fills conv csr (src node per position) AND edge-head aux ({orig edge id, col node})
__global__ __launch_bounds__(256) void k_fill(const int* __restrict__ erow, const int* __restrict__ ecol,
                                              int* __restrict__ cursor, int* __restrict__ csr,
                                              int2* __restrict__ aux) {
    int e = blockIdx.x * 256 + threadIdx.x;
    if (e < N_EDGES) {
        int c = ecol[e];
        int pos = atomicAdd(&cursor[c], 1);
        csr[pos] = erow[e];
        aux[pos] = make_int2(e, c);
    }
}

// ---------------- rows GEMM: Out[M,o_real] = act(A[M,K] @ W[K,o_real] + bias) [* rowscale] ----------------
template <int K, int O, bool RELU, bool BIAS, bool SCALE>
__global__ __launch_bounds__(256) void gemm_rows(const void* __restrict__ A, int M,
                                                 const unsigned short* __restrict__ W, int o_real,
                                                 const unsigned short* __restrict__ bias,
                                                 void* __restrict__ Out, int out_pitch,
                                                 const float* __restrict__ rowscale,
                                                 const int* aflag, const int* oflag) {
    constexpr int KP = K + 8;
    constexpr int KS = K / 32;
    constexpr int OT = O / 16;
    __shared__ short wt[O * KP];
    __shared__ float bias_s[O];
    int tid = threadIdx.x;
    for (int idx = tid; idx < K * O; idx += 256) {
        int k = idx / O, o = idx % O;
        short w = 0;
        if (o < o_real) w = (short)W[(size_t)k * o_real + o];
        wt[o * KP + k] = w;
    }
    if (BIAS) {
        for (int o = tid; o < O; o += 256) bias_s[o] = (o < o_real) ? bf2f(bias[o]) : 0.f;
    }
    __syncthreads();

    bool af32 = aflag && (*aflag != 0);
    bool of32 = oflag && (*oflag != 0);

    int wid = tid >> 6, lane = tid & 63;
    int rbase = (blockIdx.x * 4 + wid) * 32;
    if (rbase >= M) return;
    int lq = lane >> 4, lr = lane & 15;

    short8 a[2][KS];
#pragma unroll
    for (int rg = 0; rg < 2; rg++) {
        int row = rbase + rg * 16 + lr;
        if (row >= M) row = M - 1;
        if (af32) {
            const float* ap = (const float*)A + (size_t)row * K + lq * 8;
#pragma unroll
            for (int ks = 0; ks < KS; ks++) {
                f32x4 u0 = *(const f32x4*)(ap + ks * 32);
                f32x4 u1 = *(const f32x4*)(ap + ks * 32 + 4);
                short8 v;
                v[0] = (short)f2bf(u0[0]); v[1] = (short)f2bf(u0[1]);
                v[2] = (short)f2bf(u0[2]); v[3] = (short)f2bf(u0[3]);
                v[4] = (short)f2bf(u1[0]); v[5] = (short)f2bf(u1[1]);
                v[6] = (short)f2bf(u1[2]); v[7] = (short)f2bf(u1[3]);
                a[rg][ks] = v;
            }
        } else {
            const unsigned short* ap = (const unsigned short*)A + (size_t)row * K + lq * 8;
#pragma unroll
            for (int ks = 0; ks < KS; ks++) a[rg][ks] = *(const short8*)(ap + ks * 32);
        }
    }

    f32x4 acc[2][OT];
#pragma unroll
    for (int rg = 0; rg < 2; rg++)
#pragma unroll
        for (int j = 0; j < OT; j++) {
            acc[rg][j][0] = 0.f; acc[rg][j][1] = 0.f; acc[rg][j][2] = 0.f; acc[rg][j][3] = 0.f;
        }

#pragma unroll
    for (int j = 0; j < OT; j++) {
        short8 b[KS];
#pragma unroll
        for (int ks = 0; ks < KS; ks++)
            b[ks] = *(const short8*)(&wt[(lr + 16 * j) * KP + ks * 32 + lq * 8]);
#pragma unroll
        for (int rg = 0; rg < 2; rg++)
#pragma unroll
            for (int ks = 0; ks < KS; ks++)
                acc[rg][j] = __builtin_amdgcn_mfma_f32_16x16x32_bf16(a[rg][ks], b[ks], acc[rg][j], 0, 0, 0);
    }

    // D layout: col = lane&15, row = (lane>>4)*4 + reg
#pragma unroll
    for (int rg = 0; rg < 2; rg++)
#pragma unroll
        for (int j = 0; j < OT; j++)
#pragma unroll
            for (int r = 0; r < 4; r++) {
                int row = rbase + rg * 16 + lq * 4 + r;
                int col = lr + 16 * j;
                if (row < M && col < o_real) {
                    float v = acc[rg][j][r];
                    if (BIAS) v += bias_s[col];
                    if (RELU) v = fmaxf(v, 0.f);
                    if (SCALE) v *= rowscale[row];
                    size_t oi = (size_t)row * out_pitch + col;
                    if (of32) ((float*)Out)[oi] = v;
                    else ((unsigned short*)Out)[oi] = f2bf(v);
                }
            }
}

// ---------------- fused node head: logits = relu(h2@Wn1+bn1)@Wn2+bn2 ----------------
__global__ __launch_bounds__(256) void node_head(const unsigned short* __restrict__ A, int M,
                                                 const unsigned short* __restrict__ wbuf,
                                                 void* __restrict__ Out, const int* oflag) {
    __shared__ short wt1[64 * 136];  // Wn1^T [o][k], K=128
    __shared__ short zb[128 * 72];   // z[row][k], K=64, pitch 72
    __shared__ short wt2[16 * 72];   // Wn2^T [o][k], K=64 (12 real)
    __shared__ float b1[64];
    __shared__ float b2[16];
    int tid = threadIdx.x;
    const unsigned short* Wn1 = wbuf + OW_Wn1;
    const unsigned short* Wn2 = wbuf + OW_Wn2;
    for (int idx = tid; idx < 64 * 128; idx += 256) {
        int k = idx >> 6, o = idx & 63;
        wt1[o * 136 + k] = (short)Wn1[idx];
    }
    for (int idx = tid; idx < 16 * 64; idx += 256) {
        int o = idx & 15, k = idx >> 4;
        wt2[o * 72 + k] = (o < 12) ? (short)Wn2[k * 12 + o] : 0;
    }
    if (tid < 64) b1[tid] = bf2f(wbuf[OW_bn1 + tid]);
    if (tid < 16) b2[tid] = (tid < 12) ? bf2f(wbuf[OW_bn2 + tid]) : 0.f;
    __syncthreads();

    bool of32 = oflag && (*oflag != 0);
    int wid = tid >> 6, lane = tid & 63;
    int lq = lane >> 4, lr = lane & 15;
    int rbase = blockIdx.x * 128 + wid * 32;

    // A-frags K=128
    short8 a[2][4];
#pragma unroll
    for (int rg = 0; rg < 2; rg++) {
        int row = rbase + rg * 16 + lr;
        if (row >= M) row = M - 1;
        const unsigned short* ap = A + (size_t)row * 128 + lq * 8;
#pragma unroll
        for (int ks = 0; ks < 4; ks++) a[rg][ks] = *(const short8*)(ap + ks * 32);
    }

    // phase 1: z = relu(A@Wn1 + bn1), O=64 (OT=4)
    {
        f32x4 acc[2][4];
#pragma unroll
        for (int rg = 0; rg < 2; rg++)
#pragma unroll
            for (int j = 0; j < 4; j++) {
                acc[rg][j][0] = 0.f; acc[rg][j][1] = 0.f; acc[rg][j][2] = 0.f; acc[rg][j][3] = 0.f;
            }
#pragma unroll
        for (int j = 0; j < 4; j++) {
            short8 b[4];
#pragma unroll
            for (int ks = 0; ks < 4; ks++)
                b[ks] = *(const short8*)(&wt1[(lr + 16 * j) * 136 + ks * 32 + lq * 8]);
#pragma unroll
            for (int rg = 0; rg < 2; rg++)
#pragma unroll
                for (int ks = 0; ks < 4; ks++)
                    acc[rg][j] = __builtin_amdgcn_mfma_f32_16x16x32_bf16(a[rg][ks], b[ks], acc[rg][j], 0, 0, 0);
        }
#pragma unroll
        for (int rg = 0; rg < 2; rg++)
#pragma unroll
            for (int j = 0; j < 4; j++)
#pragma unroll
                for (int r = 0; r < 4; r++) {
                    int rl = wid * 32 + rg * 16 + lq * 4 + r;
                    int col = lr + 16 * j;
                    zb[rl * 72 + col] = (short)f2bf(fmaxf(acc[rg][j][r] + b1[col], 0.f));
                }
    }
    __syncthreads();

    // phase 2: logits = z@Wn2 + bn2, K=64, O=16 (12 real)
    {
        short8 a2[2][2];
#pragma unroll
        for (int rg = 0; rg < 2; rg++) {
            int rl = wid * 32 + rg * 16 + lr;
#pragma unroll
            for (int ks = 0; ks < 2; ks++)
                a2[rg][ks] = *(const short8*)(&zb[rl * 72 + ks * 32 + lq * 8]);
        }
        short8 b[2];
#pragma unroll
        for (int ks = 0; ks < 2; ks++)
            b[ks] = *(const short8*)(&wt2[lr * 72 + ks * 32 + lq * 8]);
        f32x4 acc[2];
#pragma unroll
        for (int rg = 0; rg < 2; rg++) {
            acc[rg][0] = 0.f; acc[rg][1] = 0.f; acc[rg][2] = 0.f; acc[rg][3] = 0.f;
#pragma unroll
            for (int ks = 0; ks < 2; ks++)
                acc[rg] = __builtin_amdgcn_mfma_f32_16x16x32_bf16(a2[rg][ks], b[ks], acc[rg], 0, 0, 0);
        }
#pragma unroll
        for (int rg = 0; rg < 2; rg++)
#pragma unroll
            for (int r = 0; r < 4; r++) {
                int row = rbase + rg * 16 + lq * 4 + r;
                int col = lr;
                if (row < M && col < 12) {
                    float v = acc[rg][r] + b2[col];
                    size_t oi = (size_t)row * 12 + col;
                    if (of32) ((float*)Out)[oi] = v;
                    else ((unsigned short*)Out)[oi] = f2bf(v);
                }
            }
    }
}

// ---------------- dual GEMM for edge-head P/Q — PERMUTED channel layout ----------------
__global__ __launch_bounds__(256) void gemm_pq(const unsigned short* __restrict__ A, int M,
                                               const unsigned short* __restrict__ W1,
                                               const unsigned short* __restrict__ W2,
                                               unsigned short* __restrict__ Pout,
                                               unsigned short* __restrict__ Qout) {
    __shared__ short wt[128 * 136];
    int tid = threadIdx.x;
    int wid = tid >> 6, lane = tid & 63;
    int rbase = (blockIdx.x * 4 + wid) * 32;
    int lq = lane >> 4, lr = lane & 15;

    // A fragments (loaded once, before ANY store)
    short8 a[2][4];
#pragma unroll
    for (int rg = 0; rg < 2; rg++) {
        int row = rbase + rg * 16 + lr;
        if (row >= M) row = M - 1;
        const unsigned short* ap = A + (size_t)row * 128 + lq * 8;
#pragma unroll
        for (int ks = 0; ks < 4; ks++) a[rg][ks] = *(const short8*)(ap + ks * 32);
    }

    // col = lr + 16j -> permuted position = (lr>>2)*32 + j*4 + (lr&3)
    int pc0 = (lr >> 2) * 32 + (lr & 3);

    // ---- phase P ----
    for (int idx = tid; idx < 128 * 128; idx += 256) {
        int k = idx >> 7, o = idx & 127;
        wt[o * 136 + k] = (short)W1[idx];
    }
    __syncthreads();
    {
        f32x4 acc[2][8];
#pragma unroll
        for (int rg = 0; rg < 2; rg++)
#pragma unroll
            for (int j = 0; j < 8; j++) {
                acc[rg][j][0] = 0.f; acc[rg][j][1] = 0.f; acc[rg][j][2] = 0.f; acc[rg][j][3] = 0.f;
            }
#pragma unroll
        for (int j = 0; j < 8; j++) {
            short8 b[4];
#pragma unroll
            for (int ks = 0; ks < 4; ks++)
                b[ks] = *(const short8*)(&wt[(lr + 16 * j) * 136 + ks * 32 + lq * 8]);
#pragma unroll
            for (int rg = 0; rg < 2; rg++)
#pragma unroll
                for (int ks = 0; ks < 4; ks++)
                    acc[rg][j] = __builtin_amdgcn_mfma_f32_16x16x32_bf16(a[rg][ks], b[ks], acc[rg][j], 0, 0, 0);
        }
#pragma unroll
        for (int rg = 0; rg < 2; rg++)
#pragma unroll
            for (int j = 0; j < 8; j++)
#pragma unroll
                for (int r = 0; r < 4; r++) {
                    int row = rbase + rg * 16 + lq * 4 + r;
                    if (row < M) Pout[(size_t)row * 128 + pc0 + j * 4] = f2bf(acc[rg][j][r]);
                }
    }
    __syncthreads();

    // ---- phase Q ----
    for (int idx = tid; idx < 128 * 128; idx += 256) {
        int k = idx >> 7, o = idx & 127;
        wt[o * 136 + k] = (short)W2[idx];
    }
    __syncthreads();
    {
        f32x4 acc[2][8];
#pragma unroll
        for (int rg = 0; rg < 2; rg++)
#pragma unroll
            for (int j = 0; j < 8; j++) {
                acc[rg][j][0] = 0.f; acc[rg][j][1] = 0.f; acc[rg][j][2] = 0.f; acc[rg][j][3] = 0.f;
            }
#pragma unroll
        for (int j = 0; j < 8; j++) {
            short8 b[4];
#pragma unroll
            for (int ks = 0; ks < 4; ks++)
                b[ks] = *(const short8*)(&wt[(lr + 16 * j) * 136 + ks * 32 + lq * 8]);
#pragma unroll
            for (int rg = 0; rg < 2; rg++)
#pragma unroll
                for (int ks = 0; ks < 4; ks++)
                    acc[rg][j] = __builtin_amdgcn_mfma_f32_16x16x32_bf16(a[rg][ks], b[ks], acc[rg][j], 0, 0, 0);
        }
#pragma unroll
        for (int rg = 0; rg < 2; rg++)
#pragma unroll
            for (int j = 0; j < 8; j++)
#pragma unroll
                for (int r = 0; r < 4; r++) {
                    int row = rbase + rg * 16 + lq * 4 + r;
                    if (row < M) Qout[(size_t)row * 128 + pc0 + j * 4] = f2bf(acc[rg][j][r]);
                }
    }
}

// ---------------- GCN conv: quarter-wave wide gathers — 1 dwordx4 instr fetches 4 rows ----------------
// One wave per node. Lane l: quarter q=l>>4 handles neighbor i+q, reading 16B (8 ch) at
// (l&15)*8 channels. Neighbor indices preloaded 64-wide and distributed via __shfl.
// Cross-quarter shfl_xor(16/32) reduce; self+bias post-reduce; quarter-0 writes 256B row.
// Mechanism test vs round-9/11 convs: identical bytes, ~4x fewer vmem instructions.
__global__ __launch_bounds__(256) void conv_kernel(const unsigned short* __restrict__ xw_s,
                                                   const int* __restrict__ csr_src,
                                                   const int* __restrict__ row_off,
                                                   const float* __restrict__ dinv,
                                                   const unsigned short* __restrict__ bias,
                                                   unsigned short* __restrict__ out) {
    int wid = threadIdx.x >> 6, lane = threadIdx.x & 63;
    int t = blockIdx.x * 4 + wid;  // grid = N/4, N%4==0
    int beg = row_off[t], end = row_off[t + 1];
    int d = end - beg;
    int q = lane >> 4, lr = lane & 15;

    // preload up to 64 neighbor indices (one vector load covers d<=64; Poisson(10) mean)
    int myidx = (lane < d) ? csr_src[beg + lane] : 0;

    float acc[8];
#pragma unroll
    for (int c = 0; c < 8; c++) acc[c] = 0.f;

    for (int i = 0; i < d; i += 8) {
        int p0 = i + q, p1 = i + 4 + q;
        bool ok0 = p0 < d, ok1 = p1 < d;
        int s0 = (p0 < 64) ? __shfl(myidx, p0) : (ok0 ? csr_src[beg + p0] : 0);
        int s1 = (p1 < 64) ? __shfl(myidx, p1) : (ok1 ? csr_src[beg + p1] : 0);
        if (!ok0) s0 = 0;
        if (!ok1) s1 = 0;
        short8 v0 = *(const short8*)(xw_s + (size_t)s0 * 128 + lr * 8);
        short8 v1 = *(const short8*)(xw_s + (size_t)s1 * 128 + lr * 8);
        if (ok0) {
#pragma unroll
            for (int c = 0; c < 8; c++) acc[c] += bf2f((unsigned short)v0[c]);
        }
        if (ok1) {
#pragma unroll
            for (int c = 0; c < 8; c++) acc[c] += bf2f((unsigned short)v1[c]);
        }
    }

    // cross-quarter reduce: every lane ends with the full neighbor sum for its 8 channels
#pragma unroll
    for (int c = 0; c < 8; c++) {
        acc[c] += __shfl_xor(acc[c], 16);
        acc[c] += __shfl_xor(acc[c], 32);
    }

    // self term (xw_s prescaled by dinv[src]) + bias + relu; final *dinv[t]
    short8 sv = *(const short8*)(xw_s + (size_t)t * 128 + lr * 8);
    short8 bv = *(const short8*)(bias + lr * 8);
    float dt = dinv[t];
    if (q == 0) {
        short8 o;
#pragma unroll
        for (int c = 0; c < 8; c++) {
            float v = acc[c] + bf2f((unsigned short)sv[c]);
            v = fmaxf(fmaf(v, dt, bf2f((unsigned short)bv[c])), 0.f);
            o[c] = (short)f2bf(v);
        }
        *(short8*)(out + (size_t)t * 128 + lr * 8) = o;
    }
}

// ---------------- edge head epilogue chunk helper ----------------
__device__ __forceinline__ void epi_chunk(f32x4& ov, const f32x4& acc_lo, const f32x4& acc_hi,
                                          short8 pv, short8 qv,
                                          const float* __restrict__ b1s,
                                          const float* __restrict__ w2s, int pb) {
#pragma unroll
    for (int jj = 0; jj < 2; jj++) {
        const f32x4& ac = jj ? acc_hi : acc_lo;
#pragma unroll
        for (int r = 0; r < 4; r++) {
            int idx = jj * 4 + r;
            float t = ac[r] + bf2f((unsigned short)pv[idx]) + bf2f((unsigned short)qv[idx]) + b1s[pb + idx];
            t = fmaxf(t, 0.f);
            f32x4 w2v = *(const f32x4*)(&w2s[(pb + idx) * 4]);
            ov[0] = fmaf(t, w2v[0], ov[0]);
            ov[1] = fmaf(t, w2v[1], ov[1]);
            ov[2] = fmaf(t, w2v[2], ov[2]);
            ov[3] = fmaf(t, w2v[3], ov[3]);
        }
    }
}

// ---------------- fused edge head: CSR-ordered (round-9 version — measured floor 113us) ----------------
__global__ __launch_bounds__(256) void edge_head(const void* __restrict__ ea,
                                                 const int* __restrict__ csr_src,
                                                 const int2* __restrict__ aux,
                                                 const unsigned short* __restrict__ P,
                                                 const unsigned short* __restrict__ Q,
                                                 const unsigned short* __restrict__ wbuf,
                                                 void* __restrict__ out, const int* dtflag) {
    __shared__ short wct[128 * 40];  // Wc3^T [ch][k], pitch 40
    __shared__ float w2s[128 * 4];   // permuted
    __shared__ float b1s[128];       // permuted
    int tid = threadIdx.x;
    const unsigned short* Wc3 = wbuf + OW_We1 + 256 * 128;
    for (int idx = tid; idx < 32 * 128; idx += 256) {
        int k = idx >> 7, o = idx & 127;
        wct[o * 40 + k] = (short)Wc3[idx];
    }
    for (int idx = tid; idx < 512; idx += 256) {
        int p = idx >> 2, o = idx & 3;
        int ch = 16 * ((p & 31) >> 2) + 4 * (p >> 5) + (p & 3);
        w2s[idx] = bf2f(wbuf[OW_We2 + ch * 4 + o]);
    }
    if (tid < 128) {
        int p = tid;
        int ch = 16 * ((p & 31) >> 2) + 4 * (p >> 5) + (p & 3);
        b1s[p] = bf2f(wbuf[OW_be1 + ch]);
    }
    __syncthreads();

    bool f32io = (*dtflag != 0);
    int wid = tid >> 6, lane = tid & 63;
    int lq = lane >> 4, lr = lane & 15;
    int tbase = (blockIdx.x * 4 + wid) * 2;
    int p0a = tbase * 16, p0b = p0a + 16;

    int posa = p0a + lr, posb = p0b + lr;
    bool va = posa < N_EDGES, vb = posb < N_EDGES;
    int pca = va ? posa : (N_EDGES - 1);
    int pcb = vb ? posb : (N_EDGES - 1);

    int rna = csr_src[pca], rnb = csr_src[pcb];
    int2 axa = aux[pca], axb = aux[pcb];
    int gea = axa.x, cna = axa.y;
    int geb = axb.x, cnb = axb.y;

    auto load_efrag = [&](int ge) -> short8 {
        short8 v;
        if (f32io) {
            const float* eap = (const float*)ea + (size_t)ge * 32 + lq * 8;
            f32x4 u0 = __builtin_nontemporal_load((const f32x4*)eap);
            f32x4 u1 = __builtin_nontemporal_load((const f32x4*)(eap + 4));
            v[0] = (short)f2bf(u0[0]); v[1] = (short)f2bf(u0[1]);
            v[2] = (short)f2bf(u0[2]); v[3] = (short)f2bf(u0[3]);
            v[4] = (short)f2bf(u1[0]); v[5] = (short)f2bf(u1[1]);
            v[6] = (short)f2bf(u1[2]); v[7] = (short)f2bf(u1[3]);
        } else {
            v = __builtin_nontemporal_load((const short8*)((const unsigned short*)ea + (size_t)ge * 32 + lq * 8));
        }
        return v;
    };
    short8 efA = load_efrag(gea);
    short8 efB = load_efrag(geb);

    const unsigned short* PpA = P + (size_t)rna * 128 + lq * 32;
    const unsigned short* QpA = Q + (size_t)cna * 128 + lq * 32;
    const unsigned short* PpB = P + (size_t)rnb * 128 + lq * 32;
    const unsigned short* QpB = Q + (size_t)cnb * 128 + lq * 32;

    f32x4 zero; zero[0] = 0.f; zero[1] = 0.f; zero[2] = 0.f; zero[3] = 0.f;
    f32x4 ovA = zero, ovB = zero;

    // ---- half 0: channels 0..63 (j=0..3) ----
    {
        short8 pA0 = *(const short8*)(PpA + 0);
        short8 pA1 = *(const short8*)(PpA + 8);
        short8 qA0 = *(const short8*)(QpA + 0);
        short8 qA1 = *(const short8*)(QpA + 8);
        short8 pB0 = *(const short8*)(PpB + 0);
        short8 pB1 = *(const short8*)(PpB + 8);
        short8 qB0 = *(const short8*)(QpB + 0);
        short8 qB1 = *(const short8*)(QpB + 8);
        short8 wf0 = *(const short8*)(&wct[(0 * 16 + lr) * 40 + lq * 8]);
        short8 wf1 = *(const short8*)(&wct[(1 * 16 + lr) * 40 + lq * 8]);
        short8 wf2 = *(const short8*)(&wct[(2 * 16 + lr) * 40 + lq * 8]);
        short8 wf3 = *(const short8*)(&wct[(3 * 16 + lr) * 40 + lq * 8]);
        f32x4 aA0 = __builtin_amdgcn_mfma_f32_16x16x32_bf16(wf0, efA, zero, 0, 0, 0);
        f32x4 aA1 = __builtin_amdgcn_mfma_f32_16x16x32_bf16(wf1, efA, zero, 0, 0, 0);
        f32x4 aA2 = __builtin_amdgcn_mfma_f32_16x16x32_bf16(wf2, efA, zero, 0, 0, 0);
        f32x4 aA3 = __builtin_amdgcn_mfma_f32_16x16x32_bf16(wf3, efA, zero, 0, 0, 0);
        f32x4 aB0 = __builtin_amdgcn_mfma_f32_16x16x32_bf16(wf0, efB, zero, 0, 0, 0);
        f32x4 aB1 = __builtin_amdgcn_mfma_f32_16x16x32_bf16(wf1, efB, zero, 0, 0, 0);
        f32x4 aB2 = __builtin_amdgcn_mfma_f32_16x16x32_bf16(wf2, efB, zero, 0, 0, 0);
        f32x4 aB3 = __builtin_amdgcn_mfma_f32_16x16x32_bf16(wf3, efB, zero, 0, 0, 0);
        epi_chunk(ovA, aA0, aA1, pA0, qA0, b1s, w2s, lq * 32 + 0);
        epi_chunk(ovA, aA2, aA3, pA1, qA1, b1s, w2s, lq * 32 + 8);
        epi_chunk(ovB, aB0, aB1, pB0, qB0, b1s, w2s, lq * 32 + 0);
        epi_chunk(ovB, aB2, aB3, pB1, qB1, b1s, w2s, lq * 32 + 8);
    }
    // ---- half 1: channels 64..127 (j=4..7) ----
    {
        short8 pA0 = *(const short8*)(PpA + 16);
        short8 pA1 = *(const short8*)(PpA + 24);
        short8 qA0 = *(const short8*)(QpA + 16);
        short8 qA1 = *(const short8*)(QpA + 24);
        short8 pB0 = *(const short8*)(PpB + 16);
        short8 pB1 = *(const short8*)(PpB + 24);
        short8 qB0 = *(const short8*)(QpB + 16);
        short8 qB1 = *(const short8*)(QpB + 24);
        short8 wf0 = *(const short8*)(&wct[(4 * 16 + lr) * 40 + lq * 8]);
        short8 wf1 = *(const short8*)(&wct[(5 * 16 + lr) * 40 + lq * 8]);
        short8 wf2 = *(const short8*)(&wct[(6 * 16 + lr) * 40 + lq * 8]);
        short8 wf3 = *(const short8*)(&wct[(7 * 16 + lr) * 40 + lq * 8]);
        f32x4 aA0 = __builtin_amdgcn_mfma_f32_16x16x32_bf16(wf0, efA, zero, 0, 0, 0);
        f32x4 aA1 = __builtin_amdgcn_mfma_f32_16x16x32_bf16(wf1, efA, zero, 0, 0, 0);
        f32x4 aA2 = __builtin_amdgcn_mfma_f32_16x16x32_bf16(wf2, efA, zero, 0, 0, 0);
        f32x4 aA3 = __builtin_amdgcn_mfma_f32_16x16x32_bf16(wf3, efA, zero, 0, 0, 0);
        f32x4 aB0 = __builtin_amdgcn_mfma_f32_16x16x32_bf16(wf0, efB, zero, 0, 0, 0);
        f32x4 aB1 = __builtin_amdgcn_mfma_f32_16x16x32_bf16(wf1, efB, zero, 0, 0, 0);
        f32x4 aB2 = __builtin_amdgcn_mfma_f32_16x16x32_bf16(wf2, efB, zero, 0, 0, 0);
        f32x4 aB3 = __builtin_amdgcn_mfma_f32_16x16x32_bf16(wf3, efB, zero, 0, 0, 0);
        epi_chunk(ovA, aA0, aA1, pA0, qA0, b1s, w2s, lq * 32 + 16);
        epi_chunk(ovA, aA2, aA3, pA1, qA1, b1s, w2s, lq * 32 + 24);
        epi_chunk(ovB, aB0, aB1, pB0, qB0, b1s, w2s, lq * 32 + 16);
        epi_chunk(ovB, aB2, aB3, pB1, qB1, b1s, w2s, lq * 32 + 24);
    }

    // reduce across lq (lane bits 4,5)
#pragma unroll
    for (int c = 0; c < 4; c++) {
        ovA[c] += __shfl_xor(ovA[c], 16);
        ovA[c] += __shfl_xor(ovA[c], 32);
        ovB[c] += __shfl_xor(ovB[c], 16);
        ovB[c] += __shfl_xor(ovB[c], 32);
    }
    if (lq == 0) {
        float be2_0 = bf2f(wbuf[OW_be2 + 0]), be2_1 = bf2f(wbuf[OW_be2 + 1]);
        float be2_2 = bf2f(wbuf[OW_be2 + 2]), be2_3 = bf2f(wbuf[OW_be2 + 3]);
        if (va) {
            size_t oi = (size_t)EDGE_OUT_BASE + (size_t)gea * 4;
            if (f32io) {
                f32x4 res; res[0] = ovA[0] + be2_0; res[1] = ovA[1] + be2_1;
                res[2] = ovA[2] + be2_2; res[3] = ovA[3] + be2_3;
                __builtin_nontemporal_store(res, (f32x4*)((float*)out + oi));
            } else {
                us4 res; res[0] = f2bf(ovA[0] + be2_0); res[1] = f2bf(ovA[1] + be2_1);
                res[2] = f2bf(ovA[2] + be2_2); res[3] = f2bf(ovA[3] + be2_3);
                __builtin_nontemporal_store(res, (us4*)((unsigned short*)out + oi));
            }
        }
        if (vb) {
            size_t oi = (size_t)EDGE_OUT_BASE + (size_t)geb * 4;
            if (f32io) {
                f32x4 res; res[0] = ovB[0] + be2_0; res[1] = ovB[1] + be2_1;
                res[2] = ovB[2] + be2_2; res[3] = ovB[3] + be2_3;
                __builtin_nontemporal_store(res, (f32x4*)((float*)out + oi));
            } else {
                us4 res; res[0] = f2bf(ovB[0] + be2_0); res[1] = f2bf(ovB[1] + be2_1);
                res[2] = f2bf(ovB[2] + be2_2); res[3] = f2bf(ovB[3] + be2_3);
                __builtin_nontemporal_store(res, (us4*)((unsigned short*)out + oi));
            }
        }
    }
}

// ---------------- launcher ----------------
extern "C" void kernel_launch(void* const* d_in, const int* in_sizes, int n_in,
                              void* d_out, int out_size, void* d_ws, size_t ws_size,
                              hipStream_t stream) {
    const void* x = d_in[0];
    const int* ei = (const int*)d_in[1];
    const void* ea = d_in[2];
    const int* erow = ei;
    const int* ecol = ei + N_EDGES;

    char* ws = (char*)d_ws;
    size_t off = 0;
    auto alloc = [&](size_t bytes) -> void* {
        void* p = ws + off;
        off += (bytes + 255) & ~(size_t)255;
        return p;
    };
    unsigned short* Abuf = (unsigned short*)alloc((size_t)N_NODES * 128 * 2);
    unsigned short* Bbuf = (unsigned short*)alloc((size_t)N_NODES * 128 * 2);
    int* deg = (int*)alloc((size_t)N_NODES * 4);
    int* row_off = (int*)alloc((size_t)(N_NODES + 1) * 4);
    int* cursor = (int*)alloc((size_t)N_NODES * 4);
    int* csr = (int*)alloc((size_t)N_EDGES * 4);
    int2* aux = (int2*)alloc((size_t)N_EDGES * 8);
    int* bsum = (int*)alloc(512 * 4);
    float* dinv = (float*)alloc((size_t)N_NODES * 4);
    unsigned short* wbuf = (unsigned short*)alloc((size_t)W_TOTAL * 2);
    int* dtflag = (int*)alloc(256);

    // 1. dtype detection (device-side)
    k_detect<<<1, 256, 0, stream>>>((const unsigned short*)x, dtflag);

    // 2. canonicalize weights to bf16
    WPack wp;
    for (int i = 0; i < 14; i++) wp.p[i] = d_in[3 + i];
    k_convw<<<(W_TOTAL + 255) / 256, 256, 0, stream>>>(wp, dtflag, wbuf);

    // 3. graph build
    (void)hipMemsetAsync(deg, 0, (size_t)N_NODES * 4, stream);
    k_hist<<<(N_EDGES + 255) / 256, 256, 0, stream>>>(ecol, deg);
    k_scanA<<<NB_SCAN, 256, 0, stream>>>(deg, bsum);
    k_scanB<<<1, 512, 0, stream>>>(bsum);
    k_scanC<<<NB_SCAN, 256, 0, stream>>>(deg, bsum, row_off, cursor, dinv);
    k_fill<<<(N_EDGES + 255) / 256, 256, 0, stream>>>(erow, ecol, cursor, csr, aux);

    int gB = (N_NODES + 127) / 128;
    // embed: h0 = relu(x@We+be) -> Abuf
    gemm_rows<64, 128, true, true, false><<<gB, 256, 0, stream>>>(x, N_NODES, wbuf + OW_We, 128, wbuf + OW_be, Abuf, 128, nullptr, dtflag, nullptr);
    // xw1_scaled = (h0@Wc1) * dinv[row] -> Bbuf
    gemm_rows<128, 128, false, false, true><<<gB, 256, 0, stream>>>(Abuf, N_NODES, wbuf + OW_Wc1, 128, nullptr, Bbuf, 128, dinv, nullptr, nullptr);
    conv_kernel<<<N_NODES / 4, 256, 0, stream>>>(Bbuf, csr, row_off, dinv, wbuf + OW_bc1, Abuf);
    // xw2_scaled = (h1@Wc2) * dinv[row] -> Bbuf
    gemm_rows<128, 128, false, false, true><<<gB, 256, 0, stream>>>(Abuf, N_NODES, wbuf + OW_Wc2, 128, nullptr, Bbuf, 128, dinv, nullptr, nullptr);
    conv_kernel<<<N_NODES / 4, 256, 0, stream>>>(Bbuf, csr, row_off, dinv, wbuf + OW_bc2, Abuf);
    // fused node head: logits -> d_out
    node_head<<<gB, 256, 0, stream>>>(Abuf, N_NODES, wbuf, d_out, dtflag);
    // edge head precompute (dual, permuted): P -> Bbuf, Q -> Abuf (in-place safe)
    gemm_pq<<<gB, 256, 0, stream>>>(Abuf, N_NODES, wbuf + OW_We1, wbuf + OW_We1 + 128 * 128, Bbuf, Abuf);
    // fused edge head: CSR-ordered (round-9 version), 128 positions per block
    edge_head<<<(N_EDGES + 127) / 128, 256, 0, stream>>>(ea, csr, aux, Bbuf, Abuf, wbuf, d_out, dtflag);
}